// Round 4
// baseline (104.935 us; speedup 1.0000x reference)
//
#include <hip/hip_runtime.h>

// LDDMM variational evolve: B=1, N=8192, D=3, fp32.
// dmom_i = 2g * (x_i * sum_j w_ij  -  sum_j w_ij x_j),  w_ij = K_ij <p_i,p_j>
// dx_i   = sum_j K_ij p_j,   K_ij = exp(-g |x_i - x_j|^2), g = 100.
//
// Round 4: j-tile data is wave-uniform -> precompute pre-scaled tiles into ws
// and read them with uniform indices so the backend emits s_load (SMRD).
// Inner loop = pure VALU (every instr uses <=1 SGPR operand — legal), no LDS,
// no lgkm stalls; SEG=128 -> 2048 blocks -> 8 blocks/CU (32 waves/CU).

#define TPB 256
#define ITILE 2
constexpr float GAMMA_C = 100.0f;
constexpr float LOG2E_C = 1.4426950408889634f;
constexpr float SB_C    = 2.0f * GAMMA_C * LOG2E_C;  // A.xyz = SB*x_j
constexpr float SC_C    = -GAMMA_C * LOG2E_C;        // A.w   = SC*|x_j|^2
constexpr float LN2_C   = 0.69314718055994531f;      // 2g/SB

// ---- Kernel 0: precompute pre-scaled j-tiles -------------------------------
__global__ __launch_bounds__(TPB) void lddmm_pre(
    const float* __restrict__ mom, const float* __restrict__ xpt,
    float4* __restrict__ At, float4* __restrict__ Pt, int N) {
  const int j = blockIdx.x * TPB + threadIdx.x;
  if (j < N) {
    const float bx = xpt[3*j], by = xpt[3*j+1], bz = xpt[3*j+2];
    At[j] = make_float4(SB_C*bx, SB_C*by, SB_C*bz,
                        SC_C * fmaf(bx, bx, fmaf(by, by, bz*bz)));
    Pt[j] = make_float4(mom[3*j], mom[3*j+1], mom[3*j+2], 0.f);
  }
}

// ---- Kernel A: per-segment partial sums (no LDS) ---------------------------
// grid (N/(TPB*ITILE), SEG). ws partial layout: P[c][s][i], c=0..6, [SEG][N].
__global__ __launch_bounds__(TPB, 8) void lddmm_partial(
    const float4* __restrict__ At, const float4* __restrict__ Pt,
    const float* __restrict__ mom, const float* __restrict__ xpt,
    float* __restrict__ ws, int N, int SEG, int JT) {
  const int tid = threadIdx.x;
  const int seg = blockIdx.y;
  const int jb  = seg * JT;                    // wave-uniform tile base

  const int i0 = blockIdx.x * (TPB * ITILE) + tid;
  const int i1 = i0 + TPB;

  const float x0 = xpt[3*i0], y0 = xpt[3*i0+1], z0 = xpt[3*i0+2];
  const float p0x = mom[3*i0], p0y = mom[3*i0+1], p0z = mom[3*i0+2];
  const float c0 = SC_C * fmaf(x0, x0, fmaf(y0, y0, z0*z0));
  const float x1 = xpt[3*i1], y1 = xpt[3*i1+1], z1 = xpt[3*i1+2];
  const float p1x = mom[3*i1], p1y = mom[3*i1+1], p1z = mom[3*i1+2];
  const float c1 = SC_C * fmaf(x1, x1, fmaf(y1, y1, z1*z1));

  float a0=0.f, wx0=0.f, wy0=0.f, wz0=0.f, gx0=0.f, gy0=0.f, gz0=0.f;
  float a1=0.f, wx1=0.f, wy1=0.f, wz1=0.f, gx1=0.f, gy1=0.f, gz1=0.f;

#pragma unroll 4
  for (int t = 0; t < JT; ++t) {
    const float4 A = At[jb + t];               // uniform -> s_load_dwordx4
    const float4 P = Pt[jb + t];
    // i0
    {
      const float arg = fmaf(A.x, x0, fmaf(A.y, y0, fmaf(A.z, z0, c0 + A.w)));
      const float K   = __builtin_amdgcn_exp2f(arg);          // bare v_exp_f32
      const float dot = fmaf(P.x, p0x, fmaf(P.y, p0y, P.z * p0z));
      const float w   = K * dot;
      a0 += w;
      wx0 = fmaf(w, A.x, wx0); wy0 = fmaf(w, A.y, wy0); wz0 = fmaf(w, A.z, wz0);
      gx0 = fmaf(K, P.x, gx0); gy0 = fmaf(K, P.y, gy0); gz0 = fmaf(K, P.z, gz0);
    }
    // i1
    {
      const float arg = fmaf(A.x, x1, fmaf(A.y, y1, fmaf(A.z, z1, c1 + A.w)));
      const float K   = __builtin_amdgcn_exp2f(arg);
      const float dot = fmaf(P.x, p1x, fmaf(P.y, p1y, P.z * p1z));
      const float w   = K * dot;
      a1 += w;
      wx1 = fmaf(w, A.x, wx1); wy1 = fmaf(w, A.y, wy1); wz1 = fmaf(w, A.z, wz1);
      gx1 = fmaf(K, P.x, gx1); gy1 = fmaf(K, P.y, gy1); gz1 = fmaf(K, P.z, gz1);
    }
  }

  const size_t SN = (size_t)SEG * N;
  float* p = ws + (size_t)seg * N;
  p[0*SN+i0] = a0;  p[0*SN+i1] = a1;
  p[1*SN+i0] = wx0; p[1*SN+i1] = wx1;
  p[2*SN+i0] = wy0; p[2*SN+i1] = wy1;
  p[3*SN+i0] = wz0; p[3*SN+i1] = wz1;
  p[4*SN+i0] = gx0; p[4*SN+i1] = gx1;
  p[5*SN+i0] = gy0; p[5*SN+i1] = gy1;
  p[6*SN+i0] = gz0; p[6*SN+i1] = gz1;
}

// ---- Kernel B: reduce over segments ----------------------------------------
__global__ __launch_bounds__(TPB) void lddmm_reduce(
    const float* __restrict__ ws, float* __restrict__ R, int N, int SEG) {
  const int i = blockIdx.x * TPB + threadIdx.x;
  const int c = blockIdx.y;
  const float* src = ws + (size_t)c * SEG * N + i;
  float s0 = 0.f, s1 = 0.f, s2 = 0.f, s3 = 0.f;
  int s = 0;
  for (; s + 4 <= SEG; s += 4) {
    s0 += src[(size_t)(s+0)*N]; s1 += src[(size_t)(s+1)*N];
    s2 += src[(size_t)(s+2)*N]; s3 += src[(size_t)(s+3)*N];
  }
  for (; s < SEG; ++s) s0 += src[(size_t)s*N];
  R[(size_t)c * N + i] = (s0 + s1) + (s2 + s3);
}

// ---- Kernel C: finalize ----------------------------------------------------
__global__ __launch_bounds__(TPB) void lddmm_finalize(
    const float* __restrict__ R, const float* __restrict__ xpt,
    float* __restrict__ out, int N) {
  const int i = blockIdx.x * TPB + threadIdx.x;
  const float A  = R[i];
  const float WX = R[(size_t)1*N+i], WY = R[(size_t)2*N+i], WZ = R[(size_t)3*N+i];
  const float GX = R[(size_t)4*N+i], GY = R[(size_t)5*N+i], GZ = R[(size_t)6*N+i];
  const float xi = xpt[3*i], yi = xpt[3*i+1], zi = xpt[3*i+2];
  const float TGA = 2.0f * GAMMA_C * A;
  out[3*i+0] = fmaf(TGA, xi, -LN2_C * WX);
  out[3*i+1] = fmaf(TGA, yi, -LN2_C * WY);
  out[3*i+2] = fmaf(TGA, zi, -LN2_C * WZ);
  out[3*N + 3*i + 0] = GX;
  out[3*N + 3*i + 1] = GY;
  out[3*N + 3*i + 2] = GZ;
}

// ---- Fallback (tiny ws): atomic single-kernel version ----------------------
__global__ __launch_bounds__(TPB) void lddmm_atomic(
    const float* __restrict__ mom, const float* __restrict__ xpt,
    float* __restrict__ out, int N) {
  const int i  = blockIdx.x * TPB + threadIdx.x;
  const int jb = blockIdx.y * TPB;
  __shared__ float4 sA[TPB], sP[TPB];
  {
    const int j = jb + threadIdx.x;
    const float bx = xpt[3*j], by = xpt[3*j+1], bz = xpt[3*j+2];
    sA[threadIdx.x] = make_float4(SB_C*bx, SB_C*by, SB_C*bz,
                                  SC_C * fmaf(bx, bx, fmaf(by, by, bz*bz)));
    sP[threadIdx.x] = make_float4(mom[3*j], mom[3*j+1], mom[3*j+2], 0.f);
  }
  __syncthreads();
  const float xi = xpt[3*i], yi = xpt[3*i+1], zi = xpt[3*i+2];
  const float pxi = mom[3*i], pyi = mom[3*i+1], pzi = mom[3*i+2];
  const float ci = SC_C * fmaf(xi, xi, fmaf(yi, yi, zi*zi));
  float a=0.f, wx=0.f, wy=0.f, wz=0.f, gx=0.f, gy=0.f, gz=0.f;
#pragma unroll 4
  for (int t = 0; t < TPB; ++t) {
    const float4 A = sA[t], P = sP[t];
    const float arg = fmaf(A.x, xi, fmaf(A.y, yi, fmaf(A.z, zi, ci + A.w)));
    const float K   = __builtin_amdgcn_exp2f(arg);
    const float dot = fmaf(P.x, pxi, fmaf(P.y, pyi, P.z * pzi));
    const float w   = K * dot;
    a += w;
    wx = fmaf(w, A.x, wx); wy = fmaf(w, A.y, wy); wz = fmaf(w, A.z, wz);
    gx = fmaf(K, P.x, gx); gy = fmaf(K, P.y, gy); gz = fmaf(K, P.z, gz);
  }
  const float TGA = 2.0f * GAMMA_C * a;
  atomicAdd(&out[3*i+0], fmaf(TGA, xi, -LN2_C * wx));
  atomicAdd(&out[3*i+1], fmaf(TGA, yi, -LN2_C * wy));
  atomicAdd(&out[3*i+2], fmaf(TGA, zi, -LN2_C * wz));
  atomicAdd(&out[3*N+3*i+0], gx);
  atomicAdd(&out[3*N+3*i+1], gy);
  atomicAdd(&out[3*N+3*i+2], gz);
}

extern "C" void kernel_launch(void* const* d_in, const int* in_sizes, int n_in,
                              void* d_out, int out_size, void* d_ws, size_t ws_size,
                              hipStream_t stream) {
  const float* mom = (const float*)d_in[0];   // setup_inputs order: mom first
  const float* xpt = (const float*)d_in[1];   // control_points second
  float* out = (float*)d_out;
  const int N = in_sizes[0] / 3;              // 8192

  // ws layout: [At: N float4][Pt: N float4][partials: 7*SEG*N f][R: 7*N f]
  auto need = [&](int s) {
    return (size_t)(8 + 7*s + 7) * (size_t)N * sizeof(float);
  };
  int SEG = 128;                              // 2048 partial blocks = 8/CU
  while (SEG > 2 && need(SEG) > ws_size) SEG >>= 1;

  if (need(SEG) <= ws_size) {
    const int JT = N / SEG;                   // 64 @ SEG=128
    float4* At = (float4*)d_ws;
    float4* Pt = At + N;
    float*  wsf = (float*)(Pt + N);
    float*  R   = wsf + (size_t)7 * SEG * N;

    lddmm_pre<<<N / TPB, TPB, 0, stream>>>(mom, xpt, At, Pt, N);
    dim3 gA(N / (TPB * ITILE), SEG);          // (16, 128) = 2048 blocks
    lddmm_partial<<<gA, TPB, 0, stream>>>(At, Pt, mom, xpt, wsf, N, SEG, JT);
    dim3 gB(N / TPB, 7);
    lddmm_reduce<<<gB, TPB, 0, stream>>>(wsf, R, N, SEG);
    lddmm_finalize<<<N / TPB, TPB, 0, stream>>>(R, xpt, out, N);
  } else {
    hipMemsetAsync(d_out, 0, (size_t)out_size * sizeof(float), stream);
    dim3 grid(N / TPB, N / TPB);
    lddmm_atomic<<<grid, TPB, 0, stream>>>(mom, xpt, out, N);
  }
}

// Round 5
// 97.315 us; speedup vs baseline: 1.0783x; 1.0783x over previous
//
#include <hip/hip_runtime.h>

// LDDMM variational evolve: B=1, N=8192, D=3, fp32.
// dmom_i = 2g * (x_i * sum_j w_ij  -  sum_j w_ij x_j),  w_ij = K_ij <p_i,p_j>
// dx_i   = sum_j K_ij p_j,   K_ij = exp(-g |x_i - x_j|^2), g = 100.
//
// Round 5: partial kernel is LDS-ISSUE-PIPE bound (ds_read_b128 ~12cyc/CU,
// shared by 4 SIMDs; round-3 floor = 20.5us LDS + 17us VALU ~= 39us measured).
// Fix: ITILE=4 (halves LDS traffic/pair again -> 10us) + packed fp32 via
// float2 ext-vectors / __builtin_elementwise_fma -> v_pk_fma_f32 (VALU ~10us).
// Round-4's SMRD experiment regressed (47us) — reverted to LDS staging.

#define TPB 256
#define ITILE 4
constexpr float GAMMA_C = 100.0f;
constexpr float LOG2E_C = 1.4426950408889634f;
constexpr float SB_C    = 2.0f * GAMMA_C * LOG2E_C;  // A.xyz = SB*x_j
constexpr float SC_C    = -GAMMA_C * LOG2E_C;        // A.w   = SC*|x_j|^2
constexpr float LN2_C   = 0.69314718055994531f;      // 2g/SB

typedef float v2f __attribute__((ext_vector_type(2)));

static __device__ __forceinline__ v2f splat2(float v) { return (v2f){v, v}; }
static __device__ __forceinline__ v2f fma2(v2f a, v2f b, v2f c) {
  return __builtin_elementwise_fma(a, b, c);
}

// ---- Kernel A: per-segment partial sums ------------------------------------
// grid (N/(TPB*ITILE), SEG). ws layout: P[c][s][i], c=0..6, each [SEG][N].
__global__ __launch_bounds__(TPB, 4) void lddmm_partial(
    const float* __restrict__ mom, const float* __restrict__ xpt,
    float* __restrict__ ws, int N, int SEG, int JT) {
  extern __shared__ float4 smem[];
  float4* sA = smem;        // {SB*x, SB*y, SB*z, SC*|x|^2}
  float4* sP = smem + JT;   // {px, py, pz, 0}
  const int tid = threadIdx.x;
  const int seg = blockIdx.y;

  for (int t = tid; t < JT; t += TPB) {
    const int j = seg * JT + t;
    const float bx = xpt[3*j], by = xpt[3*j+1], bz = xpt[3*j+2];
    sA[t] = make_float4(SB_C*bx, SB_C*by, SB_C*bz,
                        SC_C * fmaf(bx, bx, fmaf(by, by, bz*bz)));
    sP[t] = make_float4(mom[3*j], mom[3*j+1], mom[3*j+2], 0.f);
  }
  __syncthreads();

  const int i0 = blockIdx.x * (TPB * ITILE) + tid;
  const int i1 = i0 + TPB, i2 = i0 + 2*TPB, i3 = i0 + 3*TPB;

  // Pair A = {i0,i1}, pair B = {i2,i3}, packed as float2 lanes.
  const v2f xA = {xpt[3*i0],   xpt[3*i1]},   xB = {xpt[3*i2],   xpt[3*i3]};
  const v2f yA = {xpt[3*i0+1], xpt[3*i1+1]}, yB = {xpt[3*i2+1], xpt[3*i3+1]};
  const v2f zA = {xpt[3*i0+2], xpt[3*i1+2]}, zB = {xpt[3*i2+2], xpt[3*i3+2]};
  const v2f pxA = {mom[3*i0],   mom[3*i1]},   pxB = {mom[3*i2],   mom[3*i3]};
  const v2f pyA = {mom[3*i0+1], mom[3*i1+1]}, pyB = {mom[3*i2+1], mom[3*i3+1]};
  const v2f pzA = {mom[3*i0+2], mom[3*i1+2]}, pzB = {mom[3*i2+2], mom[3*i3+2]};
  const v2f cA = splat2(SC_C) * fma2(xA, xA, fma2(yA, yA, zA*zA));
  const v2f cB = splat2(SC_C) * fma2(xB, xB, fma2(yB, yB, zB*zB));

  v2f aA = {0,0}, wxA = {0,0}, wyA = {0,0}, wzA = {0,0};
  v2f gxA = {0,0}, gyA = {0,0}, gzA = {0,0};
  v2f aB = {0,0}, wxB = {0,0}, wyB = {0,0}, wzB = {0,0};
  v2f gxB = {0,0}, gyB = {0,0}, gzB = {0,0};

#pragma unroll 4
  for (int t = 0; t < JT; ++t) {
    const float4 A = sA[t];   // wave-uniform address -> LDS broadcast, no conflict
    const float4 P = sP[t];
    const v2f Ax = splat2(A.x), Ay = splat2(A.y), Az = splat2(A.z);
    const v2f Px = splat2(P.x), Py = splat2(P.y), Pz = splat2(P.z);
    // pair A
    {
      const v2f arg = fma2(Ax, xA, fma2(Ay, yA, fma2(Az, zA, cA + splat2(A.w))));
      v2f K; K.x = __builtin_amdgcn_exp2f(arg.x); K.y = __builtin_amdgcn_exp2f(arg.y);
      const v2f dot = fma2(Px, pxA, fma2(Py, pyA, Pz * pzA));
      const v2f w = K * dot;
      aA += w;
      wxA = fma2(w, Ax, wxA); wyA = fma2(w, Ay, wyA); wzA = fma2(w, Az, wzA);
      gxA = fma2(K, Px, gxA); gyA = fma2(K, Py, gyA); gzA = fma2(K, Pz, gzA);
    }
    // pair B
    {
      const v2f arg = fma2(Ax, xB, fma2(Ay, yB, fma2(Az, zB, cB + splat2(A.w))));
      v2f K; K.x = __builtin_amdgcn_exp2f(arg.x); K.y = __builtin_amdgcn_exp2f(arg.y);
      const v2f dot = fma2(Px, pxB, fma2(Py, pyB, Pz * pzB));
      const v2f w = K * dot;
      aB += w;
      wxB = fma2(w, Ax, wxB); wyB = fma2(w, Ay, wyB); wzB = fma2(w, Az, wzB);
      gxB = fma2(K, Px, gxB); gyB = fma2(K, Py, gyB); gzB = fma2(K, Pz, gzB);
    }
  }

  const size_t SN = (size_t)SEG * N;
  float* p = ws + (size_t)seg * N;
  p[0*SN+i0]=aA.x;  p[0*SN+i1]=aA.y;  p[0*SN+i2]=aB.x;  p[0*SN+i3]=aB.y;
  p[1*SN+i0]=wxA.x; p[1*SN+i1]=wxA.y; p[1*SN+i2]=wxB.x; p[1*SN+i3]=wxB.y;
  p[2*SN+i0]=wyA.x; p[2*SN+i1]=wyA.y; p[2*SN+i2]=wyB.x; p[2*SN+i3]=wyB.y;
  p[3*SN+i0]=wzA.x; p[3*SN+i1]=wzA.y; p[3*SN+i2]=wzB.x; p[3*SN+i3]=wzB.y;
  p[4*SN+i0]=gxA.x; p[4*SN+i1]=gxA.y; p[4*SN+i2]=gxB.x; p[4*SN+i3]=gxB.y;
  p[5*SN+i0]=gyA.x; p[5*SN+i1]=gyA.y; p[5*SN+i2]=gyB.x; p[5*SN+i3]=gyB.y;
  p[6*SN+i0]=gzA.x; p[6*SN+i1]=gzA.y; p[6*SN+i2]=gzB.x; p[6*SN+i3]=gzB.y;
}

// ---- Kernel B: reduce over segments ----------------------------------------
__global__ __launch_bounds__(TPB) void lddmm_reduce(
    const float* __restrict__ ws, float* __restrict__ R, int N, int SEG) {
  const int i = blockIdx.x * TPB + threadIdx.x;
  const int c = blockIdx.y;
  const float* src = ws + (size_t)c * SEG * N + i;
  float s0 = 0.f, s1 = 0.f, s2 = 0.f, s3 = 0.f;
  int s = 0;
  for (; s + 4 <= SEG; s += 4) {
    s0 += src[(size_t)(s+0)*N]; s1 += src[(size_t)(s+1)*N];
    s2 += src[(size_t)(s+2)*N]; s3 += src[(size_t)(s+3)*N];
  }
  for (; s < SEG; ++s) s0 += src[(size_t)s*N];
  R[(size_t)c * N + i] = (s0 + s1) + (s2 + s3);
}

// ---- Kernel C: finalize ----------------------------------------------------
__global__ __launch_bounds__(TPB) void lddmm_finalize(
    const float* __restrict__ R, const float* __restrict__ xpt,
    float* __restrict__ out, int N) {
  const int i = blockIdx.x * TPB + threadIdx.x;
  const float A  = R[i];
  const float WX = R[(size_t)1*N+i], WY = R[(size_t)2*N+i], WZ = R[(size_t)3*N+i];
  const float GX = R[(size_t)4*N+i], GY = R[(size_t)5*N+i], GZ = R[(size_t)6*N+i];
  const float xi = xpt[3*i], yi = xpt[3*i+1], zi = xpt[3*i+2];
  const float TGA = 2.0f * GAMMA_C * A;
  out[3*i+0] = fmaf(TGA, xi, -LN2_C * WX);
  out[3*i+1] = fmaf(TGA, yi, -LN2_C * WY);
  out[3*i+2] = fmaf(TGA, zi, -LN2_C * WZ);
  out[3*N + 3*i + 0] = GX;
  out[3*N + 3*i + 1] = GY;
  out[3*N + 3*i + 2] = GZ;
}

// ---- Fallback (tiny ws): atomic single-kernel version ----------------------
__global__ __launch_bounds__(TPB) void lddmm_atomic(
    const float* __restrict__ mom, const float* __restrict__ xpt,
    float* __restrict__ out, int N) {
  const int i  = blockIdx.x * TPB + threadIdx.x;
  const int jb = blockIdx.y * TPB;
  __shared__ float4 sA[TPB], sP[TPB];
  {
    const int j = jb + threadIdx.x;
    const float bx = xpt[3*j], by = xpt[3*j+1], bz = xpt[3*j+2];
    sA[threadIdx.x] = make_float4(SB_C*bx, SB_C*by, SB_C*bz,
                                  SC_C * fmaf(bx, bx, fmaf(by, by, bz*bz)));
    sP[threadIdx.x] = make_float4(mom[3*j], mom[3*j+1], mom[3*j+2], 0.f);
  }
  __syncthreads();
  const float xi = xpt[3*i], yi = xpt[3*i+1], zi = xpt[3*i+2];
  const float pxi = mom[3*i], pyi = mom[3*i+1], pzi = mom[3*i+2];
  const float ci = SC_C * fmaf(xi, xi, fmaf(yi, yi, zi*zi));
  float a=0.f, wx=0.f, wy=0.f, wz=0.f, gx=0.f, gy=0.f, gz=0.f;
#pragma unroll 4
  for (int t = 0; t < TPB; ++t) {
    const float4 A = sA[t], P = sP[t];
    const float arg = fmaf(A.x, xi, fmaf(A.y, yi, fmaf(A.z, zi, ci + A.w)));
    const float K   = __builtin_amdgcn_exp2f(arg);
    const float dot = fmaf(P.x, pxi, fmaf(P.y, pyi, P.z * pzi));
    const float w   = K * dot;
    a += w;
    wx = fmaf(w, A.x, wx); wy = fmaf(w, A.y, wy); wz = fmaf(w, A.z, wz);
    gx = fmaf(K, P.x, gx); gy = fmaf(K, P.y, gy); gz = fmaf(K, P.z, gz);
  }
  const float TGA = 2.0f * GAMMA_C * a;
  atomicAdd(&out[3*i+0], fmaf(TGA, xi, -LN2_C * wx));
  atomicAdd(&out[3*i+1], fmaf(TGA, yi, -LN2_C * wy));
  atomicAdd(&out[3*i+2], fmaf(TGA, zi, -LN2_C * wz));
  atomicAdd(&out[3*N+3*i+0], gx);
  atomicAdd(&out[3*N+3*i+1], gy);
  atomicAdd(&out[3*N+3*i+2], gz);
}

extern "C" void kernel_launch(void* const* d_in, const int* in_sizes, int n_in,
                              void* d_out, int out_size, void* d_ws, size_t ws_size,
                              hipStream_t stream) {
  const float* mom = (const float*)d_in[0];   // setup_inputs order: mom first
  const float* xpt = (const float*)d_in[1];   // control_points second
  float* out = (float*)d_out;
  const int N = in_sizes[0] / 3;              // 8192

  auto need = [&](int s) { return (size_t)(7*s + 7) * (size_t)N * sizeof(float); };
  int SEG = 128;
  while (SEG > 2 && need(SEG) > ws_size) SEG >>= 1;

  if (need(SEG) <= ws_size) {
    const int JT = N / SEG;                   // 64 @ SEG=128
    float* wsf = (float*)d_ws;
    float* R   = wsf + (size_t)7 * SEG * N;
    const size_t shmem = (size_t)JT * 2 * sizeof(float4);
    dim3 gA(N / (TPB * ITILE), SEG);          // (8, 128) = 1024 blocks, 4/CU
    lddmm_partial<<<gA, TPB, shmem, stream>>>(mom, xpt, wsf, N, SEG, JT);
    dim3 gB(N / TPB, 7);
    lddmm_reduce<<<gB, TPB, 0, stream>>>(wsf, R, N, SEG);
    lddmm_finalize<<<N / TPB, TPB, 0, stream>>>(R, xpt, out, N);
  } else {
    hipMemsetAsync(d_out, 0, (size_t)out_size * sizeof(float), stream);
    dim3 grid(N / TPB, N / TPB);
    lddmm_atomic<<<grid, TPB, 0, stream>>>(mom, xpt, out, N);
  }
}